// Round 3
// baseline (373.332 us; speedup 1.0000x reference)
//
#include <hip/hip_runtime.h>

// Problem constants
#define BB 4
#define CC 256
#define TT 8
#define HH 16
#define WW 16
#define LL 8
#define NO 8
#define DD 32
#define BT 32          // B*T
#define VV 2048        // H*W*L
#define KIN 512        // feat+pos channels for GEMM
#define EPS_ 1e-5f

typedef short bf16x8 __attribute__((ext_vector_type(8)));
typedef float f32x4 __attribute__((ext_vector_type(4)));
typedef float f32x2 __attribute__((ext_vector_type(2)));

static __device__ __forceinline__ float b2f(unsigned short u) {
    return __uint_as_float(((unsigned int)u) << 16);
}
static __device__ __forceinline__ float b2f_lo(unsigned int x) {
    return __uint_as_float(x << 16);
}
static __device__ __forceinline__ float b2f_hi(unsigned int x) {
    return __uint_as_float(x & 0xffff0000u);
}
static __device__ __forceinline__ unsigned short f2b(float f) {
    unsigned int x = __float_as_uint(f);
    unsigned int r = x + 0x7fffu + ((x >> 16) & 1u);   // RNE (finite values)
    return (unsigned short)(r >> 16);
}
static __device__ __forceinline__ unsigned int f2b_pk(float lo, float hi) {
    return (unsigned int)f2b(lo) | ((unsigned int)f2b(hi) << 16);
}
static __device__ __forceinline__ float sigm(float x) {
    return 1.0f / (1.0f + __expf(-x));
}

// ---------------------------------------------------------------------------
// K0: convert Wp[:, 0:512] -> bf16 A-matrix
// ---------------------------------------------------------------------------
__global__ __launch_bounds__(256) void k0_prep(const float* __restrict__ Wp,
                                               unsigned short* __restrict__ Wa) {
    int i = blockIdx.x * 256 + threadIdx.x;
    int o = i >> 9, k = i & 511;
    Wa[i] = f2b(Wp[o * 768 + k]);
}

// ---------------------------------------------------------------------------
// K1: transpose feat/pos (B,C,T,v) -> srcT bf16 [n][v][512] (k<256 feat, else pos)
//     + per-block partial sums (no atomics) to gpart[n][vtile][c]
// ---------------------------------------------------------------------------
__global__ __launch_bounds__(256) void k1_transpose(const float* __restrict__ features,
                                                    const float* __restrict__ pos,
                                                    unsigned short* __restrict__ srcT,
                                                    float* __restrict__ gpart) {
    const int n = blockIdx.x;          // 0..31
    const int vt = blockIdx.y;         // 0..127
    const int v0 = vt * 16;
    const int b = n >> 3, t = n & 7;
    const int tid = threadIdx.x;
    const int ty = tid >> 4;           // c offset within 16-chunk
    const int tx = tid & 15;           // v offset

    __shared__ unsigned short s1[16 * 520];   // [v][k] row stride 520 (16B-aligned rows)

    for (int cb = 0; cb < CC; cb += 16) {
        int c = cb + ty;
        size_t fidx = (((size_t)b * CC + c) * TT + t) * VV + v0 + tx;
        float f = features[fidx];
        float p = pos[fidx];
        s1[tx * 520 + c] = f2b(f);
        s1[tx * 520 + 256 + c] = f2b(p);
        // reduce f over the 16 v-lanes (lanes tx within group of 16)
        for (int d = 8; d > 0; d >>= 1) f += __shfl_down(f, d, 16);
        if (tx == 0) gpart[((size_t)n * 128 + vt) * CC + c] = f;
    }
    __syncthreads();
    // write 16 rows x 512 shorts = 1024 uint4
    const size_t base = ((size_t)n * VV + v0) * KIN;
    for (int q = tid; q < 1024; q += 256) {
        int row = q >> 6;
        int koff = (q & 63) * 8;
        *(uint4*)&srcT[base + (size_t)row * KIN + koff] = *(const uint4*)&s1[row * 520 + koff];
    }
}

// ---------------------------------------------------------------------------
// K2: reduce gpart -> glob mean; gterm[n][o] = bp[o] + sum_c Wp[o][512+c]*mean[n][c]
// ---------------------------------------------------------------------------
__global__ __launch_bounds__(256) void k2_gterm(const float* __restrict__ gpart,
                                                const float* __restrict__ Wp,
                                                const float* __restrict__ bp,
                                                float* __restrict__ gterm) {
    const int n = blockIdx.x;
    const int o = threadIdx.x;          // channel index, then output index
    __shared__ float gl[CC];
    float s = 0.0f;
    const float* gp = gpart + (size_t)n * 128 * CC + o;
    #pragma unroll 8
    for (int vt = 0; vt < 128; ++vt) s += gp[(size_t)vt * CC];
    gl[o] = s * (1.0f / (float)VV);
    __syncthreads();
    const float4* wrow = (const float4*)(Wp + (size_t)o * 768 + 512);
    const float4* g4 = (const float4*)gl;
    float acc = bp[o];
    #pragma unroll 8
    for (int c = 0; c < 64; ++c) {
        float4 w = wrow[c], g = g4[c];
        acc += w.x * g.x + w.y * g.y + w.z * g.z + w.w * g.w;
    }
    gterm[n * CC + o] = acc;
}

// ---------------------------------------------------------------------------
// K3: GEMM  projT[n][v][o] = relu( sum_k Wa[o][k]*srcT[n][v][k] + gterm[n][o] )
//     128x128 tile, 4 waves (2x2 of 64x64), 16x16x32 bf16 MFMA, BK=32
// ---------------------------------------------------------------------------
__global__ __launch_bounds__(256) void k3_gemm(const unsigned short* __restrict__ Wa,
                                               const unsigned short* __restrict__ srcT,
                                               const float* __restrict__ gterm,
                                               unsigned short* __restrict__ projT) {
    const int n  = blockIdx.x;   // batch 0..31
    const int mb = blockIdx.y;   // 0..1   (o block)
    const int nb = blockIdx.z;   // 0..15  (v block)
    const int tid = threadIdx.x;
    const int m0 = mb * 128, v0 = nb * 128;

    __shared__ short As[128 * 40];   // [row][k] stride 40 shorts (80B, 16B-aligned)
    __shared__ short Bs[128 * 40];

    const int wv = tid >> 6;
    const int lane = tid & 63;
    const int wm = wv >> 1, wn = wv & 1;
    const int lr = lane & 15, lq = lane >> 4;

    f32x4 acc[4][4];
    #pragma unroll
    for (int i = 0; i < 4; ++i)
        #pragma unroll
        for (int j = 0; j < 4; ++j)
            acc[i][j] = (f32x4){0.f, 0.f, 0.f, 0.f};

    const int row = tid >> 1, half = tid & 1;
    const unsigned short* agp = Wa + (size_t)(m0 + row) * KIN + half * 16;
    const unsigned short* bgp = srcT + ((size_t)n * VV + v0 + row) * KIN + half * 16;
    short* asp = &As[row * 40 + half * 16];
    short* bsp = &Bs[row * 40 + half * 16];

    for (int k0 = 0; k0 < KIN; k0 += 32) {
        uint4 a0 = *(const uint4*)(agp + k0);
        uint4 a1 = *(const uint4*)(agp + k0 + 8);
        uint4 b0 = *(const uint4*)(bgp + k0);
        uint4 b1 = *(const uint4*)(bgp + k0 + 8);
        __syncthreads();
        *(uint4*)asp = a0; *(uint4*)(asp + 8) = a1;
        *(uint4*)bsp = b0; *(uint4*)(bsp + 8) = b1;
        __syncthreads();

        bf16x8 af[4], bf[4];
        #pragma unroll
        for (int i = 0; i < 4; ++i)
            af[i] = *(const bf16x8*)&As[(wm * 64 + i * 16 + lr) * 40 + lq * 8];
        #pragma unroll
        for (int j = 0; j < 4; ++j)
            bf[j] = *(const bf16x8*)&Bs[(wn * 64 + j * 16 + lr) * 40 + lq * 8];
        #pragma unroll
        for (int i = 0; i < 4; ++i)
            #pragma unroll
            for (int j = 0; j < 4; ++j)
                acc[i][j] = __builtin_amdgcn_mfma_f32_16x16x32_bf16(af[i], bf[j], acc[i][j], 0, 0, 0);
    }

    // epilogue: C/D layout col=lane&15 (v), row=(lane>>4)*4+r (o)
    #pragma unroll
    for (int i = 0; i < 4; ++i) {
        const int og = m0 + wm * 64 + i * 16 + lq * 4;
        float4 g = *(const float4*)(gterm + n * CC + og);
        #pragma unroll
        for (int j = 0; j < 4; ++j) {
            const int vg = v0 + wn * 64 + j * 16 + lr;
            float x0 = fmaxf(acc[i][j][0] + g.x, 0.0f);
            float x1 = fmaxf(acc[i][j][1] + g.y, 0.0f);
            float x2 = fmaxf(acc[i][j][2] + g.z, 0.0f);
            float x3 = fmaxf(acc[i][j][3] + g.w, 0.0f);
            ushort4 st;
            st.x = f2b(x0); st.y = f2b(x1); st.z = f2b(x2); st.w = f2b(x3);
            *(ushort4*)&projT[((size_t)n * VV + vg) * CC + og] = st;
        }
    }
}

// ---------------------------------------------------------------------------
// K4: per (n,v,head): offset/weight MLPs -> 8 corner {byte-offset, weight} pairs
// ---------------------------------------------------------------------------
__global__ __launch_bounds__(256) void k4_coef(const unsigned short* __restrict__ projT,
                                               const float* __restrict__ Wo,
                                               const float* __restrict__ bo,
                                               const float* __restrict__ Ww,
                                               const float* __restrict__ bw,
                                               int2* __restrict__ pairs) {
    __shared__ float sWo[96], sWw[64], sb[5];
    const int tid = threadIdx.x;
    if (tid < 96) sWo[tid] = Wo[tid];
    if (tid < 64) sWw[tid] = Ww[tid];
    if (tid < 3)  sb[tid] = bo[tid];
    if (tid < 2)  sb[3 + tid] = bw[tid];
    __syncthreads();

    const int g = blockIdx.x * 256 + tid;       // 0..524287
    const int n = g >> 14;
    const int rem = g & 16383;
    const int v = rem >> 3;
    const int hd = rem & 7;

    // load 32 bf16 osrc values (64B contiguous)
    const uint4* up = (const uint4*)(projT + ((size_t)n * VV + v) * CC + hd * DD);
    float osrc[32];
    #pragma unroll
    for (int q = 0; q < 4; ++q) {
        uint4 u = up[q];
        unsigned int ws4[4] = {u.x, u.y, u.z, u.w};
        #pragma unroll
        for (int e = 0; e < 4; ++e) {
            osrc[q * 8 + e * 2]     = b2f_lo(ws4[e]);
            osrc[q * 8 + e * 2 + 1] = b2f_hi(ws4[e]);
        }
    }

    float o0 = sb[0], o1 = sb[1], o2 = sb[2];
    float zw = sb[4] - sb[3];
    #pragma unroll
    for (int d = 0; d < DD; ++d) {
        float t = osrc[d];
        o0 += t * sWo[3 * d + 0];
        o1 += t * sWo[3 * d + 1];
        o2 += t * sWo[3 * d + 2];
        zw += t * (sWw[2 * d + 1] - sWw[2 * d]);
    }
    const float wgt = sigm(zw);                 // softmax(...)[...,1]

    const int h = v >> 7, w = (v >> 3) & 15, l = v & 7;
    float ph = fminf(fmaxf(h * (1.0f / 15.0f), EPS_), 1.0f - EPS_);
    float pw = fminf(fmaxf(w * (1.0f / 15.0f), EPS_), 1.0f - EPS_);
    float pl = fminf(fmaxf(l * (1.0f / 7.0f),  EPS_), 1.0f - EPS_);
    float lh = __logf(ph / (1.0f - ph));
    float lw = __logf(pw / (1.0f - pw));
    float ll = __logf(pl / (1.0f - pl));

    float sph = sigm(lh + sigm(o0));
    float spw = sigm(lw + sigm(o1));
    float spl = sigm(ll + sigm(o2));
    // pix = ((2*sp-1 + 1)*S - 1)/2 = sp*S - 0.5
    float pixh = sph * 16.0f - 0.5f;
    float pixw = spw * 16.0f - 0.5f;
    float pixl = spl * 8.0f  - 0.5f;

    float flh = floorf(pixh), flw = floorf(pixw), fll = floorf(pixl);
    float fh = pixh - flh, fw = pixw - flw, fl = pixl - fll;
    int ih = (int)flh, iw = (int)flw, il = (int)fll;

    int2* pp = pairs + (size_t)g * 8;
    #pragma unroll
    for (int dz = 0; dz < 2; ++dz)
        #pragma unroll
        for (int dy = 0; dy < 2; ++dy)
            #pragma unroll
            for (int dx = 0; dx < 2; ++dx) {
                int iz = ih + dz, iy = iw + dy, ix = il + dx;
                float wt = (dz ? fh : 1.0f - fh) * (dy ? fw : 1.0f - fw) * (dx ? fl : 1.0f - fl) * wgt;
                bool valid = ((unsigned)iz < 16u) && ((unsigned)iy < 16u) && ((unsigned)ix < 8u);
                // store ROW BYTE OFFSET (row index * KIN * 2 = lin<<10) for k5
                int lin = valid ? (((iz * 16 + iy) * 8 + ix) << 10) : 0;
                float wv2 = valid ? wt : 0.0f;
                pp[dz * 4 + dy * 2 + dx] = make_int2(lin, __float_as_int(wv2));
            }
}

// ---------------------------------------------------------------------------
// K5: gather-accumulate: res[n][v][c] = sum over 64 (head,corner) of w * feat[vox][c]
//     Block = 8 voxels. Wave = 2 voxels (32 lanes x 8 channels each).
//     Branch-free, 8-deep unroll, saddr-form loads, v_pk_fma_f32 accumulate.
// ---------------------------------------------------------------------------
__global__ __launch_bounds__(256) void k5_gather(const unsigned short* __restrict__ srcT,
                                                 const int2* __restrict__ pairs,
                                                 unsigned short* __restrict__ res) {
    __shared__ int2 pr[8 * 64];
    const int n  = blockIdx.x >> 8;          // 256 blocks per n
    const int vb = (blockIdx.x & 255) * 8;   // 8 voxels per block
    const int tid = threadIdx.x;

    // stage 512 int2 (4 KB) of corner pairs: 256 threads x 16B
    {
        const int2* src = pairs + ((size_t)n * VV + vb) * 64;
        *(int4*)&pr[tid * 2] = *(const int4*)&src[tid * 2];
    }
    __syncthreads();

    const int s = tid >> 5;                  // local voxel 0..7 (half-wave each)
    const int lane = tid & 31;
    const unsigned int laneoff = (unsigned int)lane * 16u;  // 8 channels * 2B
    const char* slabB = (const char*)srcT + (size_t)n * VV * KIN * 2;
    const int2* pe = &pr[s * 64];

    f32x2 a0 = {0.f, 0.f}, a1 = {0.f, 0.f}, a2 = {0.f, 0.f}, a3 = {0.f, 0.f};

    #pragma unroll 1
    for (int e = 0; e < 64; e += 8) {
        uint4 f[8];
        float w[8];
        #pragma unroll
        for (int u = 0; u < 8; ++u) {
            int2 q = pe[e + u];
            w[u] = __int_as_float(q.y);
            f[u] = *(const uint4*)(slabB + ((unsigned int)q.x + laneoff));
        }
        #pragma unroll
        for (int u = 0; u < 8; ++u) {
            f32x2 w2 = {w[u], w[u]};
            f32x2 t0 = {b2f_lo(f[u].x), b2f_hi(f[u].x)};
            f32x2 t1 = {b2f_lo(f[u].y), b2f_hi(f[u].y)};
            f32x2 t2 = {b2f_lo(f[u].z), b2f_hi(f[u].z)};
            f32x2 t3 = {b2f_lo(f[u].w), b2f_hi(f[u].w)};
            a0 = __builtin_elementwise_fma(w2, t0, a0);
            a1 = __builtin_elementwise_fma(w2, t1, a1);
            a2 = __builtin_elementwise_fma(w2, t2, a2);
            a3 = __builtin_elementwise_fma(w2, t3, a3);
        }
    }

    uint4 st;
    st.x = f2b_pk(a0.x, a0.y);
    st.y = f2b_pk(a1.x, a1.y);
    st.z = f2b_pk(a2.x, a2.y);
    st.w = f2b_pk(a3.x, a3.y);
    *(uint4*)&res[((size_t)n * VV + vb + s) * CC + lane * 8] = st;
}

// ---------------------------------------------------------------------------
// K6: out[b][c][t][v] = features[b][c][t][v] + res[n][v][c]   (LDS transpose)
// ---------------------------------------------------------------------------
__global__ __launch_bounds__(256) void k6_final(const float* __restrict__ features,
                                                const unsigned short* __restrict__ res,
                                                float* __restrict__ out) {
    const int n = blockIdx.x;            // 0..31
    const int c0 = blockIdx.y * 64;      // 0..3 -> c tile
    const int v0 = blockIdx.z * 64;      // 0..31 -> v tile
    const int b = n >> 3, t = n & 7;
    const int tid = threadIdx.x;
    const int ty = tid >> 6, tx = tid & 63;

    __shared__ unsigned short t6[64 * 66];

    for (int vv = ty; vv < 64; vv += 4)
        t6[vv * 66 + tx] = res[((size_t)n * VV + v0 + vv) * CC + c0 + tx];
    __syncthreads();
    for (int cc = ty; cc < 64; cc += 4) {
        int c = c0 + cc;
        size_t oidx = (((size_t)b * CC + c) * TT + t) * VV + v0 + tx;
        out[oidx] = features[oidx] + b2f(t6[tx * 66 + cc]);
    }
}

// ---------------------------------------------------------------------------
extern "C" void kernel_launch(void* const* d_in, const int* in_sizes, int n_in,
                              void* d_out, int out_size, void* d_ws, size_t ws_size,
                              hipStream_t stream) {
    (void)in_sizes; (void)n_in; (void)out_size; (void)ws_size;
    const float* features = (const float*)d_in[0];
    const float* pos      = (const float*)d_in[1];
    const float* Wp       = (const float*)d_in[2];
    const float* bp       = (const float*)d_in[3];
    const float* Wo       = (const float*)d_in[4];
    const float* bo       = (const float*)d_in[5];
    const float* Ww       = (const float*)d_in[6];
    const float* bw       = (const float*)d_in[7];
    float* out = (float*)d_out;

    char* ws = (char*)d_ws;
    unsigned short* srcT  = (unsigned short*)ws;                   // 64 MiB: [32][2048][512] bf16
    unsigned short* Wa    = (unsigned short*)(ws + 67108864);      // 256 KiB
    float*          gterm = (float*)(ws + 67403776);               // 32 KiB
    unsigned short* projT = (unsigned short*)(ws + 67436544);      // 32 MiB: [32][2048][256] bf16
    int2*           pairs = (int2*)(ws + 100990976);               // 32 MiB: [32][2048][64] {off,w}
    // gpart overlays the pairs buffer (consumed by k2 before k4 writes pairs)
    float*          gpart = (float*)(ws + 100990976);              // 4 MiB: [32][128][256] f32
    unsigned short* res   = projT;                                 // overlay (projT consumed by K4)

    k0_prep<<<512, 256, 0, stream>>>(Wp, Wa);
    k1_transpose<<<dim3(32, 128), 256, 0, stream>>>(features, pos, srcT, gpart);
    k2_gterm<<<32, 256, 0, stream>>>(gpart, Wp, bp, gterm);
    k3_gemm<<<dim3(32, 2, 16), 256, 0, stream>>>(Wa, srcT, gterm, projT);
    k4_coef<<<2048, 256, 0, stream>>>(projT, Wo, bo, Ww, bw, pairs);
    k5_gather<<<8192, 256, 0, stream>>>(srcT, pairs, res);
    k6_final<<<dim3(32, 4, 32), 256, 0, stream>>>(features, res, out);
}

// Round 4
// 371.538 us; speedup vs baseline: 1.0048x; 1.0048x over previous
//
#include <hip/hip_runtime.h>

// Problem constants
#define BB 4
#define CC 256
#define TT 8
#define HH 16
#define WW 16
#define LL 8
#define NO 8
#define DD 32
#define BT 32          // B*T
#define VV 2048        // H*W*L
#define KIN 512        // feat+pos channels for GEMM
#define EPS_ 1e-5f

typedef short bf16x8 __attribute__((ext_vector_type(8)));
typedef float f32x4 __attribute__((ext_vector_type(4)));
typedef float f32x2 __attribute__((ext_vector_type(2)));

static __device__ __forceinline__ float b2f(unsigned short u) {
    return __uint_as_float(((unsigned int)u) << 16);
}
static __device__ __forceinline__ float b2f_lo(unsigned int x) {
    return __uint_as_float(x << 16);
}
static __device__ __forceinline__ float b2f_hi(unsigned int x) {
    return __uint_as_float(x & 0xffff0000u);
}
static __device__ __forceinline__ unsigned short f2b(float f) {
    unsigned int x = __float_as_uint(f);
    unsigned int r = x + 0x7fffu + ((x >> 16) & 1u);   // RNE (finite values)
    return (unsigned short)(r >> 16);
}
static __device__ __forceinline__ unsigned int f2b_pk(float lo, float hi) {
    return (unsigned int)f2b(lo) | ((unsigned int)f2b(hi) << 16);
}
static __device__ __forceinline__ float sigm(float x) {
    return 1.0f / (1.0f + __expf(-x));
}

// ---------------------------------------------------------------------------
// K0: convert Wp[:, 0:512] -> bf16 A-matrix
// ---------------------------------------------------------------------------
__global__ __launch_bounds__(256) void k0_prep(const float* __restrict__ Wp,
                                               unsigned short* __restrict__ Wa) {
    int i = blockIdx.x * 256 + threadIdx.x;
    int o = i >> 9, k = i & 511;
    Wa[i] = f2b(Wp[o * 768 + k]);
}

// ---------------------------------------------------------------------------
// K1: pure streaming transpose feat/pos (B,C,T,v) -> srcT bf16 [n][v][512]
//     Coalesced 128B row reads, conflict-free LDS (stride 258 shorts), no shuffles.
// ---------------------------------------------------------------------------
__global__ __launch_bounds__(256) void k1_transpose(const float* __restrict__ features,
                                                    const float* __restrict__ pos,
                                                    unsigned short* __restrict__ srcT) {
    const int n = blockIdx.x;          // 0..31
    const int vt = blockIdx.y;         // 0..63
    const int v0 = vt * 32;
    const int b = n >> 3, t = n & 7;
    const int tid = threadIdx.x;
    const int wv = tid >> 6;           // wave 0..3
    const int half = (tid >> 5) & 1;   // c-row within wave
    const int vl = tid & 31;           // v lane

    __shared__ unsigned short sf[32 * 258];   // [v][c] stride 258: bank-conflict-free
    __shared__ unsigned short sp[32 * 258];

    const size_t base_ft = ((size_t)b * CC * TT + t) * (size_t)VV + v0 + vl;
    #pragma unroll 8
    for (int it = 0; it < 32; ++it) {
        const int c = it * 8 + wv * 2 + half;
        const size_t idx = base_ft + (size_t)c * (TT * VV);
        float f = features[idx];
        float p = pos[idx];
        sf[vl * 258 + c] = f2b(f);
        sp[vl * 258 + c] = f2b(p);
    }
    __syncthreads();

    // write back: one v-row (256 uints: 128 feat + 128 pos) per iteration
    unsigned int* srcU = (unsigned int*)srcT;
    const size_t obase = ((size_t)n * VV + v0) * 256;
    const int ku = tid;
    #pragma unroll 4
    for (int v = 0; v < 32; ++v) {
        unsigned int u;
        if (ku < 128) u = *(const unsigned int*)&sf[v * 258 + 2 * ku];
        else          u = *(const unsigned int*)&sp[v * 258 + 2 * (ku - 128)];
        srcU[obase + (size_t)v * 256 + ku] = u;
    }
}

// ---------------------------------------------------------------------------
// K2a: partial sums of feat over v (from bf16 srcT) -> gpart[n][32][256]
// ---------------------------------------------------------------------------
__global__ __launch_bounds__(256) void k2a_gsum(const unsigned short* __restrict__ srcT,
                                                float* __restrict__ gpart) {
    const int n = blockIdx.x;        // 0..31
    const int vs = blockIdx.y;       // 0..15 (slices of 128 v)
    const int tid = threadIdx.x;
    const int ku = tid & 127;        // feat uint index (channels 2ku, 2ku+1)
    const int vh = tid >> 7;         // 0/1: which 64-v half
    const unsigned int* srcU = (const unsigned int*)srcT;
    const size_t base = ((size_t)n * VV + vs * 128 + vh * 64) * 256 + ku;
    float sl = 0.f, sh = 0.f;
    #pragma unroll 8
    for (int i = 0; i < 64; ++i) {
        unsigned int u = srcU[base + (size_t)i * 256];
        sl += b2f_lo(u);
        sh += b2f_hi(u);
    }
    float2* gp = (float2*)gpart;     // [n][32][128] float2
    gp[((size_t)n * 32 + vs * 2 + vh) * 128 + ku] = make_float2(sl, sh);
}

// ---------------------------------------------------------------------------
// K2: reduce gpart -> glob mean; gterm[n][o] = bp[o] + sum_c Wp[o][512+c]*mean[n][c]
// ---------------------------------------------------------------------------
__global__ __launch_bounds__(256) void k2_gterm(const float* __restrict__ gpart,
                                                const float* __restrict__ Wp,
                                                const float* __restrict__ bp,
                                                float* __restrict__ gterm) {
    const int n = blockIdx.x;
    const int o = threadIdx.x;          // channel index, then output index
    __shared__ float gl[CC];
    float s = 0.0f;
    const float* gp = gpart + (size_t)n * 32 * CC + o;
    #pragma unroll 8
    for (int vt = 0; vt < 32; ++vt) s += gp[vt * CC];
    gl[o] = s * (1.0f / (float)VV);
    __syncthreads();
    const float4* wrow = (const float4*)(Wp + (size_t)o * 768 + 512);
    const float4* g4 = (const float4*)gl;
    float acc = bp[o];
    #pragma unroll 8
    for (int c = 0; c < 64; ++c) {
        float4 w = wrow[c], g = g4[c];
        acc += w.x * g.x + w.y * g.y + w.z * g.z + w.w * g.w;
    }
    gterm[n * CC + o] = acc;
}

// ---------------------------------------------------------------------------
// K3: GEMM  projT[n][v][o] = relu( sum_k Wa[o][k]*srcT[n][v][k] + gterm[n][o] )
//     128x128 tile, 4 waves (2x2 of 64x64), 16x16x32 bf16 MFMA, BK=32
// ---------------------------------------------------------------------------
__global__ __launch_bounds__(256) void k3_gemm(const unsigned short* __restrict__ Wa,
                                               const unsigned short* __restrict__ srcT,
                                               const float* __restrict__ gterm,
                                               unsigned short* __restrict__ projT) {
    const int n  = blockIdx.x;   // batch 0..31
    const int mb = blockIdx.y;   // 0..1   (o block)
    const int nb = blockIdx.z;   // 0..15  (v block)
    const int tid = threadIdx.x;
    const int m0 = mb * 128, v0 = nb * 128;

    __shared__ short As[128 * 40];   // [row][k] stride 40 shorts (80B, 16B-aligned)
    __shared__ short Bs[128 * 40];

    const int wv = tid >> 6;
    const int lane = tid & 63;
    const int wm = wv >> 1, wn = wv & 1;
    const int lr = lane & 15, lq = lane >> 4;

    f32x4 acc[4][4];
    #pragma unroll
    for (int i = 0; i < 4; ++i)
        #pragma unroll
        for (int j = 0; j < 4; ++j)
            acc[i][j] = (f32x4){0.f, 0.f, 0.f, 0.f};

    const int row = tid >> 1, half = tid & 1;
    const unsigned short* agp = Wa + (size_t)(m0 + row) * KIN + half * 16;
    const unsigned short* bgp = srcT + ((size_t)n * VV + v0 + row) * KIN + half * 16;
    short* asp = &As[row * 40 + half * 16];
    short* bsp = &Bs[row * 40 + half * 16];

    for (int k0 = 0; k0 < KIN; k0 += 32) {
        uint4 a0 = *(const uint4*)(agp + k0);
        uint4 a1 = *(const uint4*)(agp + k0 + 8);
        uint4 b0 = *(const uint4*)(bgp + k0);
        uint4 b1 = *(const uint4*)(bgp + k0 + 8);
        __syncthreads();
        *(uint4*)asp = a0; *(uint4*)(asp + 8) = a1;
        *(uint4*)bsp = b0; *(uint4*)(bsp + 8) = b1;
        __syncthreads();

        bf16x8 af[4], bf[4];
        #pragma unroll
        for (int i = 0; i < 4; ++i)
            af[i] = *(const bf16x8*)&As[(wm * 64 + i * 16 + lr) * 40 + lq * 8];
        #pragma unroll
        for (int j = 0; j < 4; ++j)
            bf[j] = *(const bf16x8*)&Bs[(wn * 64 + j * 16 + lr) * 40 + lq * 8];
        #pragma unroll
        for (int i = 0; i < 4; ++i)
            #pragma unroll
            for (int j = 0; j < 4; ++j)
                acc[i][j] = __builtin_amdgcn_mfma_f32_16x16x32_bf16(af[i], bf[j], acc[i][j], 0, 0, 0);
    }

    // epilogue: C/D layout col=lane&15 (v), row=(lane>>4)*4+r (o)
    #pragma unroll
    for (int i = 0; i < 4; ++i) {
        const int og = m0 + wm * 64 + i * 16 + lq * 4;
        float4 g = *(const float4*)(gterm + n * CC + og);
        #pragma unroll
        for (int j = 0; j < 4; ++j) {
            const int vg = v0 + wn * 64 + j * 16 + lr;
            float x0 = fmaxf(acc[i][j][0] + g.x, 0.0f);
            float x1 = fmaxf(acc[i][j][1] + g.y, 0.0f);
            float x2 = fmaxf(acc[i][j][2] + g.z, 0.0f);
            float x3 = fmaxf(acc[i][j][3] + g.w, 0.0f);
            ushort4 st;
            st.x = f2b(x0); st.y = f2b(x1); st.z = f2b(x2); st.w = f2b(x3);
            *(ushort4*)&projT[((size_t)n * VV + vg) * CC + og] = st;
        }
    }
}

// ---------------------------------------------------------------------------
// K4: per (n,v,head): offset/weight MLPs -> 8 corner {byte-offset, weight} pairs
// ---------------------------------------------------------------------------
__global__ __launch_bounds__(256) void k4_coef(const unsigned short* __restrict__ projT,
                                               const float* __restrict__ Wo,
                                               const float* __restrict__ bo,
                                               const float* __restrict__ Ww,
                                               const float* __restrict__ bw,
                                               int2* __restrict__ pairs) {
    __shared__ float sWo[96], sWw[64], sb[5];
    const int tid = threadIdx.x;
    if (tid < 96) sWo[tid] = Wo[tid];
    if (tid < 64) sWw[tid] = Ww[tid];
    if (tid < 3)  sb[tid] = bo[tid];
    if (tid < 2)  sb[3 + tid] = bw[tid];
    __syncthreads();

    const int g = blockIdx.x * 256 + tid;       // 0..524287
    const int n = g >> 14;
    const int rem = g & 16383;
    const int v = rem >> 3;
    const int hd = rem & 7;

    // load 32 bf16 osrc values (64B contiguous)
    const uint4* up = (const uint4*)(projT + ((size_t)n * VV + v) * CC + hd * DD);
    float osrc[32];
    #pragma unroll
    for (int q = 0; q < 4; ++q) {
        uint4 u = up[q];
        unsigned int ws4[4] = {u.x, u.y, u.z, u.w};
        #pragma unroll
        for (int e = 0; e < 4; ++e) {
            osrc[q * 8 + e * 2]     = b2f_lo(ws4[e]);
            osrc[q * 8 + e * 2 + 1] = b2f_hi(ws4[e]);
        }
    }

    float o0 = sb[0], o1 = sb[1], o2 = sb[2];
    float zw = sb[4] - sb[3];
    #pragma unroll
    for (int d = 0; d < DD; ++d) {
        float t = osrc[d];
        o0 += t * sWo[3 * d + 0];
        o1 += t * sWo[3 * d + 1];
        o2 += t * sWo[3 * d + 2];
        zw += t * (sWw[2 * d + 1] - sWw[2 * d]);
    }
    const float wgt = sigm(zw);                 // softmax(...)[...,1]

    const int h = v >> 7, w = (v >> 3) & 15, l = v & 7;
    float ph = fminf(fmaxf(h * (1.0f / 15.0f), EPS_), 1.0f - EPS_);
    float pw = fminf(fmaxf(w * (1.0f / 15.0f), EPS_), 1.0f - EPS_);
    float pl = fminf(fmaxf(l * (1.0f / 7.0f),  EPS_), 1.0f - EPS_);
    float lh = __logf(ph / (1.0f - ph));
    float lw = __logf(pw / (1.0f - pw));
    float ll = __logf(pl / (1.0f - pl));

    float sph = sigm(lh + sigm(o0));
    float spw = sigm(lw + sigm(o1));
    float spl = sigm(ll + sigm(o2));
    // pix = ((2*sp-1 + 1)*S - 1)/2 = sp*S - 0.5
    float pixh = sph * 16.0f - 0.5f;
    float pixw = spw * 16.0f - 0.5f;
    float pixl = spl * 8.0f  - 0.5f;

    float flh = floorf(pixh), flw = floorf(pixw), fll = floorf(pixl);
    float fh = pixh - flh, fw = pixw - flw, fl = pixl - fll;
    int ih = (int)flh, iw = (int)flw, il = (int)fll;

    int2* pp = pairs + (size_t)g * 8;
    #pragma unroll
    for (int dz = 0; dz < 2; ++dz)
        #pragma unroll
        for (int dy = 0; dy < 2; ++dy)
            #pragma unroll
            for (int dx = 0; dx < 2; ++dx) {
                int iz = ih + dz, iy = iw + dy, ix = il + dx;
                float wt = (dz ? fh : 1.0f - fh) * (dy ? fw : 1.0f - fw) * (dx ? fl : 1.0f - fl) * wgt;
                bool valid = ((unsigned)iz < 16u) && ((unsigned)iy < 16u) && ((unsigned)ix < 8u);
                // store ROW BYTE OFFSET (row index * KIN * 2 = lin<<10) for k5
                int lin = valid ? (((iz * 16 + iy) * 8 + ix) << 10) : 0;
                float wv2 = valid ? wt : 0.0f;
                pp[dz * 4 + dy * 2 + dx] = make_int2(lin, __float_as_int(wv2));
            }
}

// ---------------------------------------------------------------------------
// K5: gather-accumulate: res[n][v][c] = sum over 64 (head,corner) of w * feat[vox][c]
//     Block = 8 voxels. Wave = 2 voxels (32 lanes x 8 channels each).
//     Branch-free, 8-deep unroll, saddr-form loads, v_pk_fma_f32 accumulate.
// ---------------------------------------------------------------------------
__global__ __launch_bounds__(256) void k5_gather(const unsigned short* __restrict__ srcT,
                                                 const int2* __restrict__ pairs,
                                                 unsigned short* __restrict__ res) {
    __shared__ int2 pr[8 * 64];
    const int n  = blockIdx.x >> 8;          // 256 blocks per n
    const int vb = (blockIdx.x & 255) * 8;   // 8 voxels per block
    const int tid = threadIdx.x;

    // stage 512 int2 (4 KB) of corner pairs: 256 threads x 16B
    {
        const int2* src = pairs + ((size_t)n * VV + vb) * 64;
        *(int4*)&pr[tid * 2] = *(const int4*)&src[tid * 2];
    }
    __syncthreads();

    const int s = tid >> 5;                  // local voxel 0..7 (half-wave each)
    const int lane = tid & 31;
    const unsigned int laneoff = (unsigned int)lane * 16u;  // 8 channels * 2B
    const char* slabB = (const char*)srcT + (size_t)n * VV * KIN * 2;
    const int2* pe = &pr[s * 64];

    f32x2 a0 = {0.f, 0.f}, a1 = {0.f, 0.f}, a2 = {0.f, 0.f}, a3 = {0.f, 0.f};

    #pragma unroll 1
    for (int e = 0; e < 64; e += 8) {
        uint4 f[8];
        float w[8];
        #pragma unroll
        for (int u = 0; u < 8; ++u) {
            int2 q = pe[e + u];
            w[u] = __int_as_float(q.y);
            f[u] = *(const uint4*)(slabB + ((unsigned int)q.x + laneoff));
        }
        #pragma unroll
        for (int u = 0; u < 8; ++u) {
            f32x2 w2 = {w[u], w[u]};
            f32x2 t0 = {b2f_lo(f[u].x), b2f_hi(f[u].x)};
            f32x2 t1 = {b2f_lo(f[u].y), b2f_hi(f[u].y)};
            f32x2 t2 = {b2f_lo(f[u].z), b2f_hi(f[u].z)};
            f32x2 t3 = {b2f_lo(f[u].w), b2f_hi(f[u].w)};
            a0 = __builtin_elementwise_fma(w2, t0, a0);
            a1 = __builtin_elementwise_fma(w2, t1, a1);
            a2 = __builtin_elementwise_fma(w2, t2, a2);
            a3 = __builtin_elementwise_fma(w2, t3, a3);
        }
    }

    uint4 st;
    st.x = f2b_pk(a0.x, a0.y);
    st.y = f2b_pk(a1.x, a1.y);
    st.z = f2b_pk(a2.x, a2.y);
    st.w = f2b_pk(a3.x, a3.y);
    *(uint4*)&res[((size_t)n * VV + vb + s) * CC + lane * 8] = st;
}

// ---------------------------------------------------------------------------
// K6: out[b][c][t][v] = features[b][c][t][v] + res[n][v][c]   (LDS transpose)
// ---------------------------------------------------------------------------
__global__ __launch_bounds__(256) void k6_final(const float* __restrict__ features,
                                                const unsigned short* __restrict__ res,
                                                float* __restrict__ out) {
    const int n = blockIdx.x;            // 0..31
    const int c0 = blockIdx.y * 64;      // 0..3 -> c tile
    const int v0 = blockIdx.z * 64;      // 0..31 -> v tile
    const int b = n >> 3, t = n & 7;
    const int tid = threadIdx.x;
    const int ty = tid >> 6, tx = tid & 63;

    __shared__ unsigned short t6[64 * 66];

    for (int vv = ty; vv < 64; vv += 4)
        t6[vv * 66 + tx] = res[((size_t)n * VV + v0 + vv) * CC + c0 + tx];
    __syncthreads();
    for (int cc = ty; cc < 64; cc += 4) {
        int c = c0 + cc;
        size_t oidx = (((size_t)b * CC + c) * TT + t) * VV + v0 + tx;
        out[oidx] = features[oidx] + b2f(t6[tx * 66 + cc]);
    }
}

// ---------------------------------------------------------------------------
extern "C" void kernel_launch(void* const* d_in, const int* in_sizes, int n_in,
                              void* d_out, int out_size, void* d_ws, size_t ws_size,
                              hipStream_t stream) {
    (void)in_sizes; (void)n_in; (void)out_size; (void)ws_size;
    const float* features = (const float*)d_in[0];
    const float* pos      = (const float*)d_in[1];
    const float* Wp       = (const float*)d_in[2];
    const float* bp       = (const float*)d_in[3];
    const float* Wo       = (const float*)d_in[4];
    const float* bo       = (const float*)d_in[5];
    const float* Ww       = (const float*)d_in[6];
    const float* bw       = (const float*)d_in[7];
    float* out = (float*)d_out;

    char* ws = (char*)d_ws;
    unsigned short* srcT  = (unsigned short*)ws;                   // 64 MiB: [32][2048][512] bf16
    unsigned short* Wa    = (unsigned short*)(ws + 67108864);      // 256 KiB
    float*          gterm = (float*)(ws + 67403776);               // 32 KiB
    unsigned short* projT = (unsigned short*)(ws + 67436544);      // 32 MiB: [32][2048][256] bf16
    int2*           pairs = (int2*)(ws + 100990976);               // 32 MiB: [32][2048][64] {off,w}
    // gpart overlays the pairs buffer (consumed by k2 before k4 writes pairs)
    float*          gpart = (float*)(ws + 100990976);              // 1 MiB: [32][32][256] f32
    unsigned short* res   = projT;                                 // overlay (projT consumed by K4)

    k0_prep<<<512, 256, 0, stream>>>(Wp, Wa);
    k1_transpose<<<dim3(32, 64), 256, 0, stream>>>(features, pos, srcT);
    k2a_gsum<<<dim3(32, 16), 256, 0, stream>>>(srcT, gpart);
    k2_gterm<<<32, 256, 0, stream>>>(gpart, Wp, bp, gterm);
    k3_gemm<<<dim3(32, 2, 16), 256, 0, stream>>>(Wa, srcT, gterm, projT);
    k4_coef<<<2048, 256, 0, stream>>>(projT, Wo, bo, Ww, bw, pairs);
    k5_gather<<<8192, 256, 0, stream>>>(srcT, pairs, res);
    k6_final<<<dim3(32, 4, 32), 256, 0, stream>>>(features, res, out);
}

// Round 5
// 349.257 us; speedup vs baseline: 1.0689x; 1.0638x over previous
//
#include <hip/hip_runtime.h>

// Problem constants
#define BB 4
#define CC 256
#define TT 8
#define HH 16
#define WW 16
#define LL 8
#define NO 8
#define DD 32
#define BT 32          // B*T
#define VV 2048        // H*W*L
#define KIN 512        // feat+pos channels for GEMM
#define EPS_ 1e-5f

typedef short bf16x8 __attribute__((ext_vector_type(8)));
typedef float f32x4 __attribute__((ext_vector_type(4)));
typedef float f32x2 __attribute__((ext_vector_type(2)));

static __device__ __forceinline__ float b2f(unsigned short u) {
    return __uint_as_float(((unsigned int)u) << 16);
}
static __device__ __forceinline__ float b2f_lo(unsigned int x) {
    return __uint_as_float(x << 16);
}
static __device__ __forceinline__ float b2f_hi(unsigned int x) {
    return __uint_as_float(x & 0xffff0000u);
}
static __device__ __forceinline__ unsigned short f2b(float f) {
    unsigned int x = __float_as_uint(f);
    unsigned int r = x + 0x7fffu + ((x >> 16) & 1u);   // RNE (finite values)
    return (unsigned short)(r >> 16);
}
static __device__ __forceinline__ unsigned int f2b_pk(float lo, float hi) {
    return (unsigned int)f2b(lo) | ((unsigned int)f2b(hi) << 16);
}
static __device__ __forceinline__ float sigm(float x) {
    return 1.0f / (1.0f + __expf(-x));
}

// ---------------------------------------------------------------------------
// K0: convert Wp[:, 0:512] -> bf16 A-matrix
// ---------------------------------------------------------------------------
__global__ __launch_bounds__(256) void k0_prep(const float* __restrict__ Wp,
                                               unsigned short* __restrict__ Wa) {
    int i = blockIdx.x * 256 + threadIdx.x;
    int o = i >> 9, k = i & 511;
    Wa[i] = f2b(Wp[o * 768 + k]);
}

// ---------------------------------------------------------------------------
// K1: pure streaming transpose feat/pos (B,C,T,v) -> srcT bf16 [n][v][512]
//     Coalesced 128B row reads, conflict-free LDS (stride 258 shorts), no shuffles.
// ---------------------------------------------------------------------------
__global__ __launch_bounds__(256) void k1_transpose(const float* __restrict__ features,
                                                    const float* __restrict__ pos,
                                                    unsigned short* __restrict__ srcT) {
    const int n = blockIdx.x;          // 0..31
    const int vt = blockIdx.y;         // 0..63
    const int v0 = vt * 32;
    const int b = n >> 3, t = n & 7;
    const int tid = threadIdx.x;
    const int wv = tid >> 6;           // wave 0..3
    const int half = (tid >> 5) & 1;   // c-row within wave
    const int vl = tid & 31;           // v lane

    __shared__ unsigned short sf[32 * 258];   // [v][c] stride 258: bank-conflict-free
    __shared__ unsigned short sp[32 * 258];

    const size_t base_ft = ((size_t)b * CC * TT + t) * (size_t)VV + v0 + vl;
    #pragma unroll 8
    for (int it = 0; it < 32; ++it) {
        const int c = it * 8 + wv * 2 + half;
        const size_t idx = base_ft + (size_t)c * (TT * VV);
        float f = features[idx];
        float p = pos[idx];
        sf[vl * 258 + c] = f2b(f);
        sp[vl * 258 + c] = f2b(p);
    }
    __syncthreads();

    // write back: one v-row (256 uints: 128 feat + 128 pos) per iteration
    unsigned int* srcU = (unsigned int*)srcT;
    const size_t obase = ((size_t)n * VV + v0) * 256;
    const int ku = tid;
    #pragma unroll 4
    for (int v = 0; v < 32; ++v) {
        unsigned int u;
        if (ku < 128) u = *(const unsigned int*)&sf[v * 258 + 2 * ku];
        else          u = *(const unsigned int*)&sp[v * 258 + 2 * (ku - 128)];
        srcU[obase + (size_t)v * 256 + ku] = u;
    }
}

// ---------------------------------------------------------------------------
// K2a: partial sums of feat over v (from bf16 srcT) -> gpart[n][32][256]
// ---------------------------------------------------------------------------
__global__ __launch_bounds__(256) void k2a_gsum(const unsigned short* __restrict__ srcT,
                                                float* __restrict__ gpart) {
    const int n = blockIdx.x;        // 0..31
    const int vs = blockIdx.y;       // 0..15 (slices of 128 v)
    const int tid = threadIdx.x;
    const int ku = tid & 127;        // feat uint index (channels 2ku, 2ku+1)
    const int vh = tid >> 7;         // 0/1: which 64-v half
    const unsigned int* srcU = (const unsigned int*)srcT;
    const size_t base = ((size_t)n * VV + vs * 128 + vh * 64) * 256 + ku;
    float sl = 0.f, sh = 0.f;
    #pragma unroll 8
    for (int i = 0; i < 64; ++i) {
        unsigned int u = srcU[base + (size_t)i * 256];
        sl += b2f_lo(u);
        sh += b2f_hi(u);
    }
    float2* gp = (float2*)gpart;     // [n][32][128] float2
    gp[((size_t)n * 32 + vs * 2 + vh) * 128 + ku] = make_float2(sl, sh);
}

// ---------------------------------------------------------------------------
// K2: reduce gpart -> glob mean; gterm[n][o] = bp[o] + sum_c Wp[o][512+c]*mean[n][c]
// ---------------------------------------------------------------------------
__global__ __launch_bounds__(256) void k2_gterm(const float* __restrict__ gpart,
                                                const float* __restrict__ Wp,
                                                const float* __restrict__ bp,
                                                float* __restrict__ gterm) {
    const int n = blockIdx.x;
    const int o = threadIdx.x;          // channel index, then output index
    __shared__ float gl[CC];
    float s = 0.0f;
    const float* gp = gpart + (size_t)n * 32 * CC + o;
    #pragma unroll 8
    for (int vt = 0; vt < 32; ++vt) s += gp[vt * CC];
    gl[o] = s * (1.0f / (float)VV);
    __syncthreads();
    const float4* wrow = (const float4*)(Wp + (size_t)o * 768 + 512);
    const float4* g4 = (const float4*)gl;
    float acc = bp[o];
    #pragma unroll 8
    for (int c = 0; c < 64; ++c) {
        float4 w = wrow[c], g = g4[c];
        acc += w.x * g.x + w.y * g.y + w.z * g.z + w.w * g.w;
    }
    gterm[n * CC + o] = acc;
}

// ---------------------------------------------------------------------------
// K3: GEMM  projT[n][v][o] = relu( sum_k Wa[o][k]*srcT[n][v][k] + gterm[n][o] )
//     128x128 tile, 4 waves (2x2 of 64x64), 16x16x32 bf16 MFMA, BK=32
// ---------------------------------------------------------------------------
__global__ __launch_bounds__(256) void k3_gemm(const unsigned short* __restrict__ Wa,
                                               const unsigned short* __restrict__ srcT,
                                               const float* __restrict__ gterm,
                                               unsigned short* __restrict__ projT) {
    const int n  = blockIdx.x;   // batch 0..31
    const int mb = blockIdx.y;   // 0..1   (o block)
    const int nb = blockIdx.z;   // 0..15  (v block)
    const int tid = threadIdx.x;
    const int m0 = mb * 128, v0 = nb * 128;

    __shared__ short As[128 * 40];   // [row][k] stride 40 shorts (80B, 16B-aligned)
    __shared__ short Bs[128 * 40];

    const int wv = tid >> 6;
    const int lane = tid & 63;
    const int wm = wv >> 1, wn = wv & 1;
    const int lr = lane & 15, lq = lane >> 4;

    f32x4 acc[4][4];
    #pragma unroll
    for (int i = 0; i < 4; ++i)
        #pragma unroll
        for (int j = 0; j < 4; ++j)
            acc[i][j] = (f32x4){0.f, 0.f, 0.f, 0.f};

    const int row = tid >> 1, half = tid & 1;
    const unsigned short* agp = Wa + (size_t)(m0 + row) * KIN + half * 16;
    const unsigned short* bgp = srcT + ((size_t)n * VV + v0 + row) * KIN + half * 16;
    short* asp = &As[row * 40 + half * 16];
    short* bsp = &Bs[row * 40 + half * 16];

    for (int k0 = 0; k0 < KIN; k0 += 32) {
        uint4 a0 = *(const uint4*)(agp + k0);
        uint4 a1 = *(const uint4*)(agp + k0 + 8);
        uint4 b0 = *(const uint4*)(bgp + k0);
        uint4 b1 = *(const uint4*)(bgp + k0 + 8);
        __syncthreads();
        *(uint4*)asp = a0; *(uint4*)(asp + 8) = a1;
        *(uint4*)bsp = b0; *(uint4*)(bsp + 8) = b1;
        __syncthreads();

        bf16x8 af[4], bf[4];
        #pragma unroll
        for (int i = 0; i < 4; ++i)
            af[i] = *(const bf16x8*)&As[(wm * 64 + i * 16 + lr) * 40 + lq * 8];
        #pragma unroll
        for (int j = 0; j < 4; ++j)
            bf[j] = *(const bf16x8*)&Bs[(wn * 64 + j * 16 + lr) * 40 + lq * 8];
        #pragma unroll
        for (int i = 0; i < 4; ++i)
            #pragma unroll
            for (int j = 0; j < 4; ++j)
                acc[i][j] = __builtin_amdgcn_mfma_f32_16x16x32_bf16(af[i], bf[j], acc[i][j], 0, 0, 0);
    }

    // epilogue: C/D layout col=lane&15 (v), row=(lane>>4)*4+r (o)
    #pragma unroll
    for (int i = 0; i < 4; ++i) {
        const int og = m0 + wm * 64 + i * 16 + lq * 4;
        float4 g = *(const float4*)(gterm + n * CC + og);
        #pragma unroll
        for (int j = 0; j < 4; ++j) {
            const int vg = v0 + wn * 64 + j * 16 + lr;
            float x0 = fmaxf(acc[i][j][0] + g.x, 0.0f);
            float x1 = fmaxf(acc[i][j][1] + g.y, 0.0f);
            float x2 = fmaxf(acc[i][j][2] + g.z, 0.0f);
            float x3 = fmaxf(acc[i][j][3] + g.w, 0.0f);
            ushort4 st;
            st.x = f2b(x0); st.y = f2b(x1); st.z = f2b(x2); st.w = f2b(x3);
            *(ushort4*)&projT[((size_t)n * VV + vg) * CC + og] = st;
        }
    }
}

// ---------------------------------------------------------------------------
// K4: per (n,v,head): offset/weight MLPs -> 8 corner {byte-offset, weight} pairs
// ---------------------------------------------------------------------------
__global__ __launch_bounds__(256) void k4_coef(const unsigned short* __restrict__ projT,
                                               const float* __restrict__ Wo,
                                               const float* __restrict__ bo,
                                               const float* __restrict__ Ww,
                                               const float* __restrict__ bw,
                                               int2* __restrict__ pairs) {
    __shared__ float sWo[96], sWw[64], sb[5];
    const int tid = threadIdx.x;
    if (tid < 96) sWo[tid] = Wo[tid];
    if (tid < 64) sWw[tid] = Ww[tid];
    if (tid < 3)  sb[tid] = bo[tid];
    if (tid < 2)  sb[3 + tid] = bw[tid];
    __syncthreads();

    const int g = blockIdx.x * 256 + tid;       // 0..524287
    const int n = g >> 14;
    const int rem = g & 16383;
    const int v = rem >> 3;
    const int hd = rem & 7;

    // load 32 bf16 osrc values (64B contiguous)
    const uint4* up = (const uint4*)(projT + ((size_t)n * VV + v) * CC + hd * DD);
    float osrc[32];
    #pragma unroll
    for (int q = 0; q < 4; ++q) {
        uint4 u = up[q];
        unsigned int ws4[4] = {u.x, u.y, u.z, u.w};
        #pragma unroll
        for (int e = 0; e < 4; ++e) {
            osrc[q * 8 + e * 2]     = b2f_lo(ws4[e]);
            osrc[q * 8 + e * 2 + 1] = b2f_hi(ws4[e]);
        }
    }

    float o0 = sb[0], o1 = sb[1], o2 = sb[2];
    float zw = sb[4] - sb[3];
    #pragma unroll
    for (int d = 0; d < DD; ++d) {
        float t = osrc[d];
        o0 += t * sWo[3 * d + 0];
        o1 += t * sWo[3 * d + 1];
        o2 += t * sWo[3 * d + 2];
        zw += t * (sWw[2 * d + 1] - sWw[2 * d]);
    }
    const float wgt = sigm(zw);                 // softmax(...)[...,1]

    const int h = v >> 7, w = (v >> 3) & 15, l = v & 7;
    float ph = fminf(fmaxf(h * (1.0f / 15.0f), EPS_), 1.0f - EPS_);
    float pw = fminf(fmaxf(w * (1.0f / 15.0f), EPS_), 1.0f - EPS_);
    float pl = fminf(fmaxf(l * (1.0f / 7.0f),  EPS_), 1.0f - EPS_);
    float lh = __logf(ph / (1.0f - ph));
    float lw = __logf(pw / (1.0f - pw));
    float ll = __logf(pl / (1.0f - pl));

    float sph = sigm(lh + sigm(o0));
    float spw = sigm(lw + sigm(o1));
    float spl = sigm(ll + sigm(o2));
    // pix = ((2*sp-1 + 1)*S - 1)/2 = sp*S - 0.5
    float pixh = sph * 16.0f - 0.5f;
    float pixw = spw * 16.0f - 0.5f;
    float pixl = spl * 8.0f  - 0.5f;

    float flh = floorf(pixh), flw = floorf(pixw), fll = floorf(pixl);
    float fh = pixh - flh, fw = pixw - flw, fl = pixl - fll;
    int ih = (int)flh, iw = (int)flw, il = (int)fll;

    int2* pp = pairs + (size_t)g * 8;
    #pragma unroll
    for (int dz = 0; dz < 2; ++dz)
        #pragma unroll
        for (int dy = 0; dy < 2; ++dy)
            #pragma unroll
            for (int dx = 0; dx < 2; ++dx) {
                int iz = ih + dz, iy = iw + dy, ix = il + dx;
                float wt = (dz ? fh : 1.0f - fh) * (dy ? fw : 1.0f - fw) * (dx ? fl : 1.0f - fl) * wgt;
                bool valid = ((unsigned)iz < 16u) && ((unsigned)iy < 16u) && ((unsigned)ix < 8u);
                // store ROW BYTE OFFSET (row index * KIN * 2 = lin<<10) for k5
                int lin = valid ? (((iz * 16 + iy) * 8 + ix) << 10) : 0;
                float wv2 = valid ? wt : 0.0f;
                pp[dz * 4 + dy * 2 + dx] = make_int2(lin, __float_as_int(wv2));
            }
}

// ---------------------------------------------------------------------------
// K5: gather-accumulate with per-voxel corner DEDUP.
//     One wave per voxel: bitonic-sort 64 (row,w) pairs by row, merge equal
//     rows (segmented sum), compact unique rows, then gather only unique rows
//     (one 512B row per iteration, 64 lanes x 8B, 8-deep pipelined).
// ---------------------------------------------------------------------------
__global__ __launch_bounds__(256) void k5_gather(const unsigned short* __restrict__ srcT,
                                                 const int2* __restrict__ pairs,
                                                 unsigned short* __restrict__ res) {
    __shared__ int   sK[4 * 64];
    __shared__ float sW[4 * 64];
    const int tid = threadIdx.x;
    const int wid = tid >> 6;
    const int lane = tid & 63;
    const int gv = blockIdx.x * 4 + wid;      // global voxel slot 0..65535
    const int n = gv >> 11;
    const int v = gv & 2047;

    int2 q = pairs[(size_t)gv * 64 + lane];
    int key = q.x;                            // row byte offset (0..2047<<10)
    float w = __int_as_float(q.y);

    // bitonic sort 64 lanes by key (ascending)
    #pragma unroll
    for (int k = 2; k <= 64; k <<= 1) {
        #pragma unroll
        for (int j = k >> 1; j > 0; j >>= 1) {
            int pk = __shfl_xor(key, j);
            float pw = __shfl_xor(w, j);
            bool keepMin = (((lane & k) == 0) == ((lane & j) == 0));
            bool take = keepMin ? (pk < key) : (pk > key);
            if (take) { key = pk; w = pw; }
        }
    }
    // segmented inclusive sum of w over equal-key runs
    #pragma unroll
    for (int d = 1; d < 64; d <<= 1) {
        float tw = __shfl_up(w, d);
        int   tk = __shfl_up(key, d);
        if (lane >= d && tk == key) w += tw;
    }
    int nk = __shfl_down(key, 1);
    bool tail = (lane == 63) || (nk != key);  // last lane of each run holds run total
    unsigned long long mask = __ballot(tail);
    int cnt = __popcll(mask);
    int cidx = __popcll(mask & ((1ull << lane) - 1ull));

    // compact unique (key, total w) into per-wave LDS; pad with (0, 0)
    sK[wid * 64 + lane] = 0;
    sW[wid * 64 + lane] = 0.0f;
    __syncthreads();
    if (tail) { sK[wid * 64 + cidx] = key; sW[wid * 64 + cidx] = w; }
    __syncthreads();
    int ck = sK[wid * 64 + lane];
    float cw = sW[wid * 64 + lane];

    // gather unique rows: 64 lanes x 8B (4 channels each), 8 loads in flight
    const char* slabB = (const char*)srcT + (size_t)n * VV * KIN * 2 + lane * 8;
    float a0 = 0.f, a1 = 0.f, a2 = 0.f, a3 = 0.f;
    const int iters = (cnt + 7) & ~7;
    #pragma unroll 1
    for (int e = 0; e < iters; e += 8) {
        uint2 f[8]; float wv[8];
        #pragma unroll
        for (int u = 0; u < 8; ++u) {
            int rk = __shfl(ck, e + u);       // uniform index -> readlane
            wv[u] = __shfl(cw, e + u);
            f[u] = *(const uint2*)(slabB + (unsigned)rk);
        }
        #pragma unroll
        for (int u = 0; u < 8; ++u) {
            a0 = fmaf(wv[u], b2f_lo(f[u].x), a0);
            a1 = fmaf(wv[u], b2f_hi(f[u].x), a1);
            a2 = fmaf(wv[u], b2f_lo(f[u].y), a2);
            a3 = fmaf(wv[u], b2f_hi(f[u].y), a3);
        }
    }

    uint2 st;
    st.x = f2b_pk(a0, a1);
    st.y = f2b_pk(a2, a3);
    *(uint2*)&res[((size_t)n * VV + v) * CC + lane * 4] = st;
}

// ---------------------------------------------------------------------------
// K6: out[b][c][t][v] = features[b][c][t][v] + res[n][v][c]   (LDS transpose)
// ---------------------------------------------------------------------------
__global__ __launch_bounds__(256) void k6_final(const float* __restrict__ features,
                                                const unsigned short* __restrict__ res,
                                                float* __restrict__ out) {
    const int n = blockIdx.x;            // 0..31
    const int c0 = blockIdx.y * 64;      // 0..3 -> c tile
    const int v0 = blockIdx.z * 64;      // 0..31 -> v tile
    const int b = n >> 3, t = n & 7;
    const int tid = threadIdx.x;
    const int ty = tid >> 6, tx = tid & 63;

    __shared__ unsigned short t6[64 * 66];

    for (int vv = ty; vv < 64; vv += 4)
        t6[vv * 66 + tx] = res[((size_t)n * VV + v0 + vv) * CC + c0 + tx];
    __syncthreads();
    for (int cc = ty; cc < 64; cc += 4) {
        int c = c0 + cc;
        size_t oidx = (((size_t)b * CC + c) * TT + t) * VV + v0 + tx;
        out[oidx] = features[oidx] + b2f(t6[tx * 66 + cc]);
    }
}

// ---------------------------------------------------------------------------
extern "C" void kernel_launch(void* const* d_in, const int* in_sizes, int n_in,
                              void* d_out, int out_size, void* d_ws, size_t ws_size,
                              hipStream_t stream) {
    (void)in_sizes; (void)n_in; (void)out_size; (void)ws_size;
    const float* features = (const float*)d_in[0];
    const float* pos      = (const float*)d_in[1];
    const float* Wp       = (const float*)d_in[2];
    const float* bp       = (const float*)d_in[3];
    const float* Wo       = (const float*)d_in[4];
    const float* bo       = (const float*)d_in[5];
    const float* Ww       = (const float*)d_in[6];
    const float* bw       = (const float*)d_in[7];
    float* out = (float*)d_out;

    char* ws = (char*)d_ws;
    unsigned short* srcT  = (unsigned short*)ws;                   // 64 MiB: [32][2048][512] bf16
    unsigned short* Wa    = (unsigned short*)(ws + 67108864);      // 256 KiB
    float*          gterm = (float*)(ws + 67403776);               // 32 KiB
    unsigned short* projT = (unsigned short*)(ws + 67436544);      // 32 MiB: [32][2048][256] bf16
    int2*           pairs = (int2*)(ws + 100990976);               // 32 MiB: [32][2048][64] {off,w}
    // gpart overlays the pairs buffer (consumed by k2 before k4 writes pairs)
    float*          gpart = (float*)(ws + 100990976);              // 1 MiB: [32][32][256] f32
    unsigned short* res   = projT;                                 // overlay (projT consumed by K4)

    k0_prep<<<512, 256, 0, stream>>>(Wp, Wa);
    k1_transpose<<<dim3(32, 64), 256, 0, stream>>>(features, pos, srcT);
    k2a_gsum<<<dim3(32, 16), 256, 0, stream>>>(srcT, gpart);
    k2_gterm<<<32, 256, 0, stream>>>(gpart, Wp, bp, gterm);
    k3_gemm<<<dim3(32, 2, 16), 256, 0, stream>>>(Wa, srcT, gterm, projT);
    k4_coef<<<2048, 256, 0, stream>>>(projT, Wo, bo, Ww, bw, pairs);
    k5_gather<<<16384, 256, 0, stream>>>(srcT, pairs, res);
    k6_final<<<dim3(32, 4, 32), 256, 0, stream>>>(features, res, out);
}

// Round 6
// 344.292 us; speedup vs baseline: 1.0843x; 1.0144x over previous
//
#include <hip/hip_runtime.h>

// Problem constants
#define BB 4
#define CC 256
#define TT 8
#define HH 16
#define WW 16
#define LL 8
#define NO 8
#define DD 32
#define BT 32          // B*T
#define VV 2048        // H*W*L
#define KIN 512        // feat+pos channels for GEMM
#define EPS_ 1e-5f

typedef short bf16x8 __attribute__((ext_vector_type(8)));
typedef float f32x4 __attribute__((ext_vector_type(4)));
typedef float f32x2 __attribute__((ext_vector_type(2)));

static __device__ __forceinline__ float b2f(unsigned short u) {
    return __uint_as_float(((unsigned int)u) << 16);
}
static __device__ __forceinline__ float b2f_lo(unsigned int x) {
    return __uint_as_float(x << 16);
}
static __device__ __forceinline__ float b2f_hi(unsigned int x) {
    return __uint_as_float(x & 0xffff0000u);
}
static __device__ __forceinline__ unsigned short f2b(float f) {
    unsigned int x = __float_as_uint(f);
    unsigned int r = x + 0x7fffu + ((x >> 16) & 1u);   // RNE (finite values)
    return (unsigned short)(r >> 16);
}
static __device__ __forceinline__ unsigned int f2b_pk(float lo, float hi) {
    return (unsigned int)f2b(lo) | ((unsigned int)f2b(hi) << 16);
}
static __device__ __forceinline__ float sigm(float x) {
    return 1.0f / (1.0f + __expf(-x));
}

// ---------------------------------------------------------------------------
// K0: convert Wp[:, 0:512] -> bf16 A-matrix
// ---------------------------------------------------------------------------
__global__ __launch_bounds__(256) void k0_prep(const float* __restrict__ Wp,
                                               unsigned short* __restrict__ Wa) {
    int i = blockIdx.x * 256 + threadIdx.x;
    int o = i >> 9, k = i & 511;
    Wa[i] = f2b(Wp[o * 768 + k]);
}

// ---------------------------------------------------------------------------
// K1: streaming transpose feat/pos (B,C,T,v) -> srcT bf16 [n][v][512]
//     Per block: 32 v x 128 c (half channels). float4 loads (8 in flight),
//     16.6 KB LDS -> 8 blocks/CU. blockIdx.x = v-tile for DRAM-sequential sweep.
// ---------------------------------------------------------------------------
__global__ __launch_bounds__(256) void k1_transpose(const float* __restrict__ features,
                                                    const float* __restrict__ pos,
                                                    unsigned short* __restrict__ srcT) {
    const int vt = blockIdx.x;         // 0..63 (fastest: adjacent blocks sweep v)
    const int ch = blockIdx.y;         // 0..1 channel half
    const int n  = blockIdx.z;         // 0..31
    const int v0 = vt * 32;
    const int b = n >> 3, t = n & 7;
    const int tid = threadIdx.x;
    const int wv = tid >> 6;           // wave 0..3
    const int lane = tid & 63;
    const int cg = lane >> 3;          // c offset within wave-iter (0..7)
    const int vg = lane & 7;           // v group (4 consecutive v)

    __shared__ unsigned short sf[32 * 130];   // [v][lc] stride 130
    __shared__ unsigned short sp[32 * 130];

    // load phase: 4 iterations, each (feat,pos) float4 -> 8 loads in flight
    const int lcbase = wv * 8 + cg;    // local c before iter stride 32
    const size_t base = (((size_t)b * CC + ch * 128) * TT + t) * (size_t)VV + v0 + vg * 4;
    float4 fv[4], pv[4];
    #pragma unroll
    for (int it = 0; it < 4; ++it) {
        const size_t idx = base + (size_t)(lcbase + it * 32) * (TT * VV);
        fv[it] = *(const float4*)(features + idx);
        pv[it] = *(const float4*)(pos + idx);
    }
    #pragma unroll
    for (int it = 0; it < 4; ++it) {
        const int lc = lcbase + it * 32;
        const int vb = vg * 4;
        sf[(vb + 0) * 130 + lc] = f2b(fv[it].x);
        sf[(vb + 1) * 130 + lc] = f2b(fv[it].y);
        sf[(vb + 2) * 130 + lc] = f2b(fv[it].z);
        sf[(vb + 3) * 130 + lc] = f2b(fv[it].w);
        sp[(vb + 0) * 130 + lc] = f2b(pv[it].x);
        sp[(vb + 1) * 130 + lc] = f2b(pv[it].y);
        sp[(vb + 2) * 130 + lc] = f2b(pv[it].z);
        sp[(vb + 3) * 130 + lc] = f2b(pv[it].w);
    }
    __syncthreads();

    // write-back: 2 v-rows per iteration; wave = 64 consecutive uints (256B)
    unsigned int* srcU = (unsigned int*)srcT;
    const int vi = tid >> 7;           // 0/1
    const int j  = tid & 127;          // 0..63 feat-uint, 64..127 pos-uint
    const int kuint = (j < 64) ? (ch * 64 + j) : (128 + ch * 64 + (j - 64));
    const int lj2 = (j < 64) ? (2 * j) : (2 * (j - 64));
    const unsigned short* lsrc = (j < 64) ? sf : sp;
    const size_t obase = ((size_t)n * VV + v0) * 256 + kuint;
    #pragma unroll 8
    for (int vp = 0; vp < 32; vp += 2) {
        const int v = vp + vi;
        srcU[obase + (size_t)v * 256] = *(const unsigned int*)&lsrc[v * 130 + lj2];
    }
}

// ---------------------------------------------------------------------------
// K2a: partial sums of feat over v (from bf16 srcT) -> gpart[n][32][256]
// ---------------------------------------------------------------------------
__global__ __launch_bounds__(256) void k2a_gsum(const unsigned short* __restrict__ srcT,
                                                float* __restrict__ gpart) {
    const int n = blockIdx.x;        // 0..31
    const int vs = blockIdx.y;       // 0..15 (slices of 128 v)
    const int tid = threadIdx.x;
    const int ku = tid & 127;        // feat uint index (channels 2ku, 2ku+1)
    const int vh = tid >> 7;         // 0/1: which 64-v half
    const unsigned int* srcU = (const unsigned int*)srcT;
    const size_t base = ((size_t)n * VV + vs * 128 + vh * 64) * 256 + ku;
    float sl = 0.f, sh = 0.f;
    #pragma unroll 8
    for (int i = 0; i < 64; ++i) {
        unsigned int u = srcU[base + (size_t)i * 256];
        sl += b2f_lo(u);
        sh += b2f_hi(u);
    }
    float2* gp = (float2*)gpart;     // [n][32][128] float2
    gp[((size_t)n * 32 + vs * 2 + vh) * 128 + ku] = make_float2(sl, sh);
}

// ---------------------------------------------------------------------------
// K2: reduce gpart -> glob mean; gterm[n][o] = bp[o] + sum_c Wp[o][512+c]*mean[n][c]
// ---------------------------------------------------------------------------
__global__ __launch_bounds__(256) void k2_gterm(const float* __restrict__ gpart,
                                                const float* __restrict__ Wp,
                                                const float* __restrict__ bp,
                                                float* __restrict__ gterm) {
    const int n = blockIdx.x;
    const int o = threadIdx.x;          // channel index, then output index
    __shared__ float gl[CC];
    float s = 0.0f;
    const float* gp = gpart + (size_t)n * 32 * CC + o;
    #pragma unroll 8
    for (int vt = 0; vt < 32; ++vt) s += gp[vt * CC];
    gl[o] = s * (1.0f / (float)VV);
    __syncthreads();
    const float4* wrow = (const float4*)(Wp + (size_t)o * 768 + 512);
    const float4* g4 = (const float4*)gl;
    float acc = bp[o];
    #pragma unroll 8
    for (int c = 0; c < 64; ++c) {
        float4 w = wrow[c], g = g4[c];
        acc += w.x * g.x + w.y * g.y + w.z * g.z + w.w * g.w;
    }
    gterm[n * CC + o] = acc;
}

// ---------------------------------------------------------------------------
// K3: GEMM  projT[n][v][o] = relu( sum_k Wa[o][k]*srcT[n][v][k] + gterm[n][o] )
//     128x128 tile, 4 waves (2x2 of 64x64), 16x16x32 bf16 MFMA, BK=32
// ---------------------------------------------------------------------------
__global__ __launch_bounds__(256) void k3_gemm(const unsigned short* __restrict__ Wa,
                                               const unsigned short* __restrict__ srcT,
                                               const float* __restrict__ gterm,
                                               unsigned short* __restrict__ projT) {
    const int n  = blockIdx.x;   // batch 0..31
    const int mb = blockIdx.y;   // 0..1   (o block)
    const int nb = blockIdx.z;   // 0..15  (v block)
    const int tid = threadIdx.x;
    const int m0 = mb * 128, v0 = nb * 128;

    __shared__ short As[128 * 40];   // [row][k] stride 40 shorts (80B, 16B-aligned)
    __shared__ short Bs[128 * 40];

    const int wv = tid >> 6;
    const int lane = tid & 63;
    const int wm = wv >> 1, wn = wv & 1;
    const int lr = lane & 15, lq = lane >> 4;

    f32x4 acc[4][4];
    #pragma unroll
    for (int i = 0; i < 4; ++i)
        #pragma unroll
        for (int j = 0; j < 4; ++j)
            acc[i][j] = (f32x4){0.f, 0.f, 0.f, 0.f};

    const int row = tid >> 1, half = tid & 1;
    const unsigned short* agp = Wa + (size_t)(m0 + row) * KIN + half * 16;
    const unsigned short* bgp = srcT + ((size_t)n * VV + v0 + row) * KIN + half * 16;
    short* asp = &As[row * 40 + half * 16];
    short* bsp = &Bs[row * 40 + half * 16];

    for (int k0 = 0; k0 < KIN; k0 += 32) {
        uint4 a0 = *(const uint4*)(agp + k0);
        uint4 a1 = *(const uint4*)(agp + k0 + 8);
        uint4 b0 = *(const uint4*)(bgp + k0);
        uint4 b1 = *(const uint4*)(bgp + k0 + 8);
        __syncthreads();
        *(uint4*)asp = a0; *(uint4*)(asp + 8) = a1;
        *(uint4*)bsp = b0; *(uint4*)(bsp + 8) = b1;
        __syncthreads();

        bf16x8 af[4], bf[4];
        #pragma unroll
        for (int i = 0; i < 4; ++i)
            af[i] = *(const bf16x8*)&As[(wm * 64 + i * 16 + lr) * 40 + lq * 8];
        #pragma unroll
        for (int j = 0; j < 4; ++j)
            bf[j] = *(const bf16x8*)&Bs[(wn * 64 + j * 16 + lr) * 40 + lq * 8];
        #pragma unroll
        for (int i = 0; i < 4; ++i)
            #pragma unroll
            for (int j = 0; j < 4; ++j)
                acc[i][j] = __builtin_amdgcn_mfma_f32_16x16x32_bf16(af[i], bf[j], acc[i][j], 0, 0, 0);
    }

    // epilogue: C/D layout col=lane&15 (v), row=(lane>>4)*4+r (o)
    #pragma unroll
    for (int i = 0; i < 4; ++i) {
        const int og = m0 + wm * 64 + i * 16 + lq * 4;
        float4 g = *(const float4*)(gterm + n * CC + og);
        #pragma unroll
        for (int j = 0; j < 4; ++j) {
            const int vg = v0 + wn * 64 + j * 16 + lr;
            float x0 = fmaxf(acc[i][j][0] + g.x, 0.0f);
            float x1 = fmaxf(acc[i][j][1] + g.y, 0.0f);
            float x2 = fmaxf(acc[i][j][2] + g.z, 0.0f);
            float x3 = fmaxf(acc[i][j][3] + g.w, 0.0f);
            ushort4 st;
            st.x = f2b(x0); st.y = f2b(x1); st.z = f2b(x2); st.w = f2b(x3);
            *(ushort4*)&projT[((size_t)n * VV + vg) * CC + og] = st;
        }
    }
}

// ---------------------------------------------------------------------------
// K4: per (n,v,head): offset/weight MLPs -> 8 corner {byte-offset, weight} pairs
// ---------------------------------------------------------------------------
__global__ __launch_bounds__(256) void k4_coef(const unsigned short* __restrict__ projT,
                                               const float* __restrict__ Wo,
                                               const float* __restrict__ bo,
                                               const float* __restrict__ Ww,
                                               const float* __restrict__ bw,
                                               int2* __restrict__ pairs) {
    __shared__ float sWo[96], sWw[64], sb[5];
    const int tid = threadIdx.x;
    if (tid < 96) sWo[tid] = Wo[tid];
    if (tid < 64) sWw[tid] = Ww[tid];
    if (tid < 3)  sb[tid] = bo[tid];
    if (tid < 2)  sb[3 + tid] = bw[tid];
    __syncthreads();

    const int g = blockIdx.x * 256 + tid;       // 0..524287
    const int n = g >> 14;
    const int rem = g & 16383;
    const int v = rem >> 3;
    const int hd = rem & 7;

    // load 32 bf16 osrc values (64B contiguous)
    const uint4* up = (const uint4*)(projT + ((size_t)n * VV + v) * CC + hd * DD);
    float osrc[32];
    #pragma unroll
    for (int q = 0; q < 4; ++q) {
        uint4 u = up[q];
        unsigned int ws4[4] = {u.x, u.y, u.z, u.w};
        #pragma unroll
        for (int e = 0; e < 4; ++e) {
            osrc[q * 8 + e * 2]     = b2f_lo(ws4[e]);
            osrc[q * 8 + e * 2 + 1] = b2f_hi(ws4[e]);
        }
    }

    float o0 = sb[0], o1 = sb[1], o2 = sb[2];
    float zw = sb[4] - sb[3];
    #pragma unroll
    for (int d = 0; d < DD; ++d) {
        float t = osrc[d];
        o0 += t * sWo[3 * d + 0];
        o1 += t * sWo[3 * d + 1];
        o2 += t * sWo[3 * d + 2];
        zw += t * (sWw[2 * d + 1] - sWw[2 * d]);
    }
    const float wgt = sigm(zw);                 // softmax(...)[...,1]

    const int h = v >> 7, w = (v >> 3) & 15, l = v & 7;
    float ph = fminf(fmaxf(h * (1.0f / 15.0f), EPS_), 1.0f - EPS_);
    float pw = fminf(fmaxf(w * (1.0f / 15.0f), EPS_), 1.0f - EPS_);
    float pl = fminf(fmaxf(l * (1.0f / 7.0f),  EPS_), 1.0f - EPS_);
    float lh = __logf(ph / (1.0f - ph));
    float lw = __logf(pw / (1.0f - pw));
    float ll = __logf(pl / (1.0f - pl));

    float sph = sigm(lh + sigm(o0));
    float spw = sigm(lw + sigm(o1));
    float spl = sigm(ll + sigm(o2));
    // pix = ((2*sp-1 + 1)*S - 1)/2 = sp*S - 0.5
    float pixh = sph * 16.0f - 0.5f;
    float pixw = spw * 16.0f - 0.5f;
    float pixl = spl * 8.0f  - 0.5f;

    float flh = floorf(pixh), flw = floorf(pixw), fll = floorf(pixl);
    float fh = pixh - flh, fw = pixw - flw, fl = pixl - fll;
    int ih = (int)flh, iw = (int)flw, il = (int)fll;

    int2* pp = pairs + (size_t)g * 8;
    #pragma unroll
    for (int dz = 0; dz < 2; ++dz)
        #pragma unroll
        for (int dy = 0; dy < 2; ++dy)
            #pragma unroll
            for (int dx = 0; dx < 2; ++dx) {
                int iz = ih + dz, iy = iw + dy, ix = il + dx;
                float wt = (dz ? fh : 1.0f - fh) * (dy ? fw : 1.0f - fw) * (dx ? fl : 1.0f - fl) * wgt;
                bool valid = ((unsigned)iz < 16u) && ((unsigned)iy < 16u) && ((unsigned)ix < 8u);
                // store ROW BYTE OFFSET (row index * KIN * 2 = lin<<10) for k5
                int lin = valid ? (((iz * 16 + iy) * 8 + ix) << 10) : 0;
                float wv2 = valid ? wt : 0.0f;
                pp[dz * 4 + dy * 2 + dx] = make_int2(lin, __float_as_int(wv2));
            }
}

// ---------------------------------------------------------------------------
// K5: gather-accumulate with per-voxel corner DEDUP.
//     One wave per voxel: bitonic-sort 64 (row,w) pairs by row, merge equal
//     rows (segmented sum), compact unique rows, then gather only unique rows
//     (one 512B row per iteration, 64 lanes x 8B, 8-deep pipelined).
// ---------------------------------------------------------------------------
__global__ __launch_bounds__(256) void k5_gather(const unsigned short* __restrict__ srcT,
                                                 const int2* __restrict__ pairs,
                                                 unsigned short* __restrict__ res) {
    __shared__ int   sK[4 * 64];
    __shared__ float sW[4 * 64];
    const int tid = threadIdx.x;
    const int wid = tid >> 6;
    const int lane = tid & 63;
    const int gv = blockIdx.x * 4 + wid;      // global voxel slot 0..65535
    const int n = gv >> 11;
    const int v = gv & 2047;

    int2 q = pairs[(size_t)gv * 64 + lane];
    int key = q.x;                            // row byte offset (0..2047<<10)
    float w = __int_as_float(q.y);

    // bitonic sort 64 lanes by key (ascending)
    #pragma unroll
    for (int k = 2; k <= 64; k <<= 1) {
        #pragma unroll
        for (int j = k >> 1; j > 0; j >>= 1) {
            int pk = __shfl_xor(key, j);
            float pw = __shfl_xor(w, j);
            bool keepMin = (((lane & k) == 0) == ((lane & j) == 0));
            bool take = keepMin ? (pk < key) : (pk > key);
            if (take) { key = pk; w = pw; }
        }
    }
    // segmented inclusive sum of w over equal-key runs
    #pragma unroll
    for (int d = 1; d < 64; d <<= 1) {
        float tw = __shfl_up(w, d);
        int   tk = __shfl_up(key, d);
        if (lane >= d && tk == key) w += tw;
    }
    int nk = __shfl_down(key, 1);
    bool tail = (lane == 63) || (nk != key);  // last lane of each run holds run total
    unsigned long long mask = __ballot(tail);
    int cnt = __popcll(mask);
    int cidx = __popcll(mask & ((1ull << lane) - 1ull));

    // compact unique (key, total w) into per-wave LDS; pad with (0, 0)
    sK[wid * 64 + lane] = 0;
    sW[wid * 64 + lane] = 0.0f;
    __syncthreads();
    if (tail) { sK[wid * 64 + cidx] = key; sW[wid * 64 + cidx] = w; }
    __syncthreads();
    int ck = sK[wid * 64 + lane];
    float cw = sW[wid * 64 + lane];

    // gather unique rows: 64 lanes x 8B (4 channels each), 8 loads in flight
    const char* slabB = (const char*)srcT + (size_t)n * VV * KIN * 2 + lane * 8;
    float a0 = 0.f, a1 = 0.f, a2 = 0.f, a3 = 0.f;
    const int iters = (cnt + 7) & ~7;
    #pragma unroll 1
    for (int e = 0; e < iters; e += 8) {
        uint2 f[8]; float wv[8];
        #pragma unroll
        for (int u = 0; u < 8; ++u) {
            int rk = __shfl(ck, e + u);       // uniform index -> readlane
            wv[u] = __shfl(cw, e + u);
            f[u] = *(const uint2*)(slabB + (unsigned)rk);
        }
        #pragma unroll
        for (int u = 0; u < 8; ++u) {
            a0 = fmaf(wv[u], b2f_lo(f[u].x), a0);
            a1 = fmaf(wv[u], b2f_hi(f[u].x), a1);
            a2 = fmaf(wv[u], b2f_lo(f[u].y), a2);
            a3 = fmaf(wv[u], b2f_hi(f[u].y), a3);
        }
    }

    uint2 st;
    st.x = f2b_pk(a0, a1);
    st.y = f2b_pk(a2, a3);
    *(uint2*)&res[((size_t)n * VV + v) * CC + lane * 4] = st;
}

// ---------------------------------------------------------------------------
// K6: out[b][c][t][v] = features[b][c][t][v] + res[n][v][c]   (LDS transpose)
// ---------------------------------------------------------------------------
__global__ __launch_bounds__(256) void k6_final(const float* __restrict__ features,
                                                const unsigned short* __restrict__ res,
                                                float* __restrict__ out) {
    const int n = blockIdx.x;            // 0..31
    const int c0 = blockIdx.y * 64;      // 0..3 -> c tile
    const int v0 = blockIdx.z * 64;      // 0..31 -> v tile
    const int b = n >> 3, t = n & 7;
    const int tid = threadIdx.x;
    const int ty = tid >> 6, tx = tid & 63;

    __shared__ unsigned short t6[64 * 66];

    for (int vv = ty; vv < 64; vv += 4)
        t6[vv * 66 + tx] = res[((size_t)n * VV + v0 + vv) * CC + c0 + tx];
    __syncthreads();
    for (int cc = ty; cc < 64; cc += 4) {
        int c = c0 + cc;
        size_t oidx = (((size_t)b * CC + c) * TT + t) * VV + v0 + tx;
        out[oidx] = features[oidx] + b2f(t6[tx * 66 + cc]);
    }
}

// ---------------------------------------------------------------------------
extern "C" void kernel_launch(void* const* d_in, const int* in_sizes, int n_in,
                              void* d_out, int out_size, void* d_ws, size_t ws_size,
                              hipStream_t stream) {
    (void)in_sizes; (void)n_in; (void)out_size; (void)ws_size;
    const float* features = (const float*)d_in[0];
    const float* pos      = (const float*)d_in[1];
    const float* Wp       = (const float*)d_in[2];
    const float* bp       = (const float*)d_in[3];
    const float* Wo       = (const float*)d_in[4];
    const float* bo       = (const float*)d_in[5];
    const float* Ww       = (const float*)d_in[6];
    const float* bw       = (const float*)d_in[7];
    float* out = (float*)d_out;

    char* ws = (char*)d_ws;
    unsigned short* srcT  = (unsigned short*)ws;                   // 64 MiB: [32][2048][512] bf16
    unsigned short* Wa    = (unsigned short*)(ws + 67108864);      // 256 KiB
    float*          gterm = (float*)(ws + 67403776);               // 32 KiB
    unsigned short* projT = (unsigned short*)(ws + 67436544);      // 32 MiB: [32][2048][256] bf16
    int2*           pairs = (int2*)(ws + 100990976);               // 32 MiB: [32][2048][64] {off,w}
    // gpart overlays the pairs buffer (consumed by k2 before k4 writes pairs)
    float*          gpart = (float*)(ws + 100990976);              // 1 MiB: [32][32][256] f32
    unsigned short* res   = projT;                                 // overlay (projT consumed by K4)

    k0_prep<<<512, 256, 0, stream>>>(Wp, Wa);
    k1_transpose<<<dim3(64, 2, 32), 256, 0, stream>>>(features, pos, srcT);
    k2a_gsum<<<dim3(32, 16), 256, 0, stream>>>(srcT, gpart);
    k2_gterm<<<32, 256, 0, stream>>>(gpart, Wp, bp, gterm);
    k3_gemm<<<dim3(32, 2, 16), 256, 0, stream>>>(Wa, srcT, gterm, projT);
    k4_coef<<<2048, 256, 0, stream>>>(projT, Wo, bo, Ww, bw, pairs);
    k5_gather<<<16384, 256, 0, stream>>>(srcT, pairs, res);
    k6_final<<<dim3(32, 4, 32), 256, 0, stream>>>(features, res, out);
}